// Round 8
// baseline (1109.989 us; speedup 1.0000x reference)
//
#include <hip/hip_runtime.h>
#include <math.h>

// LPCDARTS forward on MI355X — v10: 2x per-wave tile (4 rows x 64 o).
// v9 post-mortem: manual A-pipeline was a null (compiler already did it,
// VGPR unchanged at 68).  Revised model: per-wave MFMA duty ~11% with fixed
// distributed stalls; dilute them by doubling MFMA work per wave per tap.
// Wave = 4 out rows x 64 o = 32 C-frags; 32 MFMA per tap vs same 4 A-loads.
// Block = 4 waves = 16-row strip, 76.8 KB LDS, 2 blocks/CU.  Node 0 keeps
// the 2-row variant (512 blocks to fill the GPU).

#define NB 64
#define CF 256
#define PC 64
#define HW 32
#define NEDGE 10
#define TAPS 81

#define TC 40
#define CSTR 40            // halves per pixel (32 ch + 8 pad) = 80 B
#define ROWSTR (TC * CSTR) // 1600 halves per row

typedef _Float16 f16x8 __attribute__((ext_vector_type(8)));
typedef _Float16 f16x2 __attribute__((ext_vector_type(2)));
typedef float f32x4 __attribute__((ext_vector_type(4)));

// ---------------- softmax over arch params (10 edges x 12 ops) -------------
__global__ void softmax_kernel(const float* __restrict__ arch,
                               const float* __restrict__ norms,
                               float* __restrict__ sw) {
    int e = threadIdx.x;
    if (e >= NEDGE) return;
    int node = 0, i = e;
    while (i > node) { i -= node + 1; node++; }
    float norm = fmaxf(norms[node * 5 + i], 1e-5f);
    const float* a = arch + (node * 5 + i) * 12;
    float v[12];
    float m = -3.0e38f;
    for (int k = 0; k < 12; ++k) { v[k] = a[k] / norm; m = fmaxf(m, v[k]); }
    float ssum = 0.f;
    for (int k = 0; k < 12; ++k) { v[k] = expf(v[k] - m); ssum += v[k]; }
    float inv = 1.0f / ssum;
    for (int k = 0; k < 12; ++k) sw[e * 12 + k] = v[k] * inv;
}

// ---------------- build combined 9x9 fp16 weights --------------------------
// Layout: Wh[e][tap][g][o][c32] halves (g = c>>5).  NO identity term (fp32
// epilogue handles w[0]).
__global__ void build_w(const float* __restrict__ w3, const float* __restrict__ w5,
                        const float* __restrict__ w7, const float* __restrict__ w1,
                        const float* __restrict__ s3dw, const float* __restrict__ s3pw,
                        const float* __restrict__ s5dw, const float* __restrict__ s5pw,
                        const float* __restrict__ d3, const float* __restrict__ d5,
                        const float* __restrict__ sw, _Float16* __restrict__ Wh) {
    int gid = blockIdx.x * 256 + threadIdx.x;  // 10*81*2*64*32 = 3,317,760
    int c32 = gid & 31;
    int o   = (gid >> 5) & 63;
    int g   = (gid >> 11) & 1;
    int t2  = gid >> 12;          // e*81 + tap
    int tap = t2 % TAPS;
    int e   = t2 / TAPS;
    int c   = (g << 5) | c32;

    int dy = tap / 9 - 4, dx = tap % 9 - 4;
    const float* w = sw + e * 12;
    int eoc = (e * 64 + o) * 64 + c;
    int ec  = e * 64 + c;
    float val = 0.f;
    int ady = dy < 0 ? -dy : dy, adx = dx < 0 ? -dx : dx;
    if (ady <= 1 && adx <= 1) {
        val += w[1] * w3[eoc * 9 + (dy + 1) * 3 + (dx + 1)];
        val += w[7] * s3pw[eoc] * s3dw[ec * 9 + (dy + 1) * 3 + (dx + 1)];
    }
    if (ady <= 2 && adx <= 2) {
        val += w[2] * w5[eoc * 25 + (dy + 2) * 5 + (dx + 2)];
        val += w[8] * s5pw[eoc] * s5dw[ec * 25 + (dy + 2) * 5 + (dx + 2)];
        if (((dy | dx) & 1) == 0)
            val += w[9] * d3[eoc * 9 + (dy / 2 + 1) * 3 + (dx / 2 + 1)];
    }
    if (ady <= 3 && adx <= 3)
        val += w[3] * w7[eoc * 49 + (dy + 3) * 7 + (dx + 3)];
    if (((dy | dx) & 1) == 0)
        val += w[10] * d5[eoc * 25 + (dy / 2 + 2) * 5 + (dx / 2 + 2)];
    if (dy == 0 && dx == 0)
        val += w[4] * w1[eoc];     // identity w[0] deliberately NOT added
    Wh[gid] = (_Float16)val;
}

// ---------------- pools (also zero-inits acc) ------------------------------
__global__ void pool_node(const float* __restrict__ s0, const float* __restrict__ s1,
                          const float* __restrict__ s2, const float* __restrict__ s3,
                          float* __restrict__ acc, const float* __restrict__ sw,
                          int ebase, int nedges) {
    int gid = blockIdx.x * 256 + threadIdx.x;  // over S/8 = 2,097,152
    int x0 = (gid & 3) << 3;                   // 0,8,16,24
    int y  = (gid >> 2) & 31;
    size_t plane = (size_t)(gid >> 7);         // (n, c)
    const float* states[4] = {s0, s1, s2, s3};
    float outv[8];
    #pragma unroll
    for (int j = 0; j < 8; ++j) outv[j] = 0.f;

    for (int i = 0; i < nedges; ++i) {
        const float* base = states[i] + (plane << 10);
        float colmax[10], colsum[10];
        #pragma unroll
        for (int j = 0; j < 10; ++j) { colmax[j] = -3.0e38f; colsum[j] = 0.f; }
        #pragma unroll
        for (int dr = -1; dr <= 1; ++dr) {
            int r = y + dr;
            if ((unsigned)r < 32u) {
                const float* rp = base + (r << 5);
                float vals[10];
                vals[0] = (x0 > 0) ? rp[x0 - 1] : 0.f;
                f32x4 m0 = *(const f32x4*)(rp + x0);
                f32x4 m1 = *(const f32x4*)(rp + x0 + 4);
                vals[1] = m0.x; vals[2] = m0.y; vals[3] = m0.z; vals[4] = m0.w;
                vals[5] = m1.x; vals[6] = m1.y; vals[7] = m1.z; vals[8] = m1.w;
                vals[9] = (x0 < 24) ? rp[x0 + 8] : 0.f;
                #pragma unroll
                for (int j = 0; j < 10; ++j) {
                    colsum[j] += vals[j];
                    colmax[j] = fmaxf(colmax[j], vals[j]);
                }
            }
        }
        if (x0 == 0)  colmax[0] = -3.0e38f;
        if (x0 == 24) colmax[9] = -3.0e38f;

        float wmax = sw[(ebase + i) * 12 + 5];
        float wavg = sw[(ebase + i) * 12 + 6] * (1.0f / 9.0f);
        #pragma unroll
        for (int j = 0; j < 8; ++j) {
            float mx = fmaxf(fmaxf(colmax[j], colmax[j + 1]), colmax[j + 2]);
            float sm = colsum[j] + colsum[j + 1] + colsum[j + 2];
            outv[j] += wmax * mx + wavg * sm;
        }
    }
    float* op = acc + (plane << 10) + (y << 5) + x0;
    ((f32x4*)op)[0] = (f32x4){outv[0], outv[1], outv[2], outv[3]};
    ((f32x4*)op)[1] = (f32x4){outv[4], outv[5], outv[6], outv[7]};
}

// ---------------- MFMA conv for all edges of one node ----------------------
// WR = output rows per wave (2 or 4).  Block: 256 thr = 4 waves; strip =
// 4*WR rows; tile = strip+8 rows.  Per tap: 4*WR*2 MFMAs vs 4 A-loads.
// Grid: (64n x strips, nedges, 2 ch-groups).  Epilogue: atomicAdd.
template <int WR>
__global__ __launch_bounds__(256, WR == 2 ? 3 : 2) void conv_node(
    const float* __restrict__ s0, const float* __restrict__ s1,
    const float* __restrict__ s2, const float* __restrict__ s3,
    float* __restrict__ acc, const _Float16* __restrict__ Wh,
    const int* __restrict__ idxg, const float* __restrict__ sw, int ebase) {
    constexpr int SR = 4 * WR;            // strip rows
    constexpr int TRR = SR + 8;           // staged rows (incl 2x4 halo)
    constexpr int STRIPS = 32 / SR;
    __shared__ __align__(16) _Float16 tile[TRR * ROWSTR];

    int i = blockIdx.y;
    int e = ebase + i;
    const float* sarr[4] = {s0, s1, s2, s3};
    const float* s = sarr[i];
    int g = blockIdx.z;

    int t  = threadIdx.x;
    int qy = blockIdx.x & (STRIPS - 1);
    int n  = blockIdx.x / STRIPS;
    int y0 = qy * SR;

    // zero whole tile (interior rewritten by staging; border stays 0)
    for (int l = t; l < TRR * ROWSTR / 8; l += 256)
        ((f32x4*)tile)[l] = (f32x4){0.f, 0.f, 0.f, 0.f};

    int lane = t & 63;
    int wave = __builtin_amdgcn_readfirstlane(t >> 6);
    int aoff = ((lane & 15) << 5) + ((lane >> 4) << 3);   // halves into [o][c32] chunk
    int boff = (lane & 15) * CSTR + ((lane >> 4) << 3);   // halves into tile row

    int sx = t & 31;        // staging x
    int cp = t >> 5;        // staging channel-pair slot 0..7

    f32x4 a[4][2 * WR];     // [o-frag][row*2+colblk]
    #pragma unroll
    for (int k = 0; k < 4; ++k)
        #pragma unroll
        for (int p = 0; p < 2 * WR; ++p) a[k][p] = (f32x4){0.f, 0.f, 0.f, 0.f};

    const int* ide = idxg + e * PC;

    __syncthreads();

    // ---- stage this block's 32-channel group fp32->fp16 into [row][px][c] -
    #pragma unroll
    for (int sub = 0; sub < 2; ++sub) {
        int c2 = cp + (sub << 3);                  // 0..15
        int ca = (g << 5) + (c2 << 1);
        const float* pa = s + (((size_t)n * CF + ide[ca]) << 10);
        const float* pb = s + (((size_t)n * CF + ide[ca + 1]) << 10);
        #pragma unroll
        for (int r = 0; r < TRR; ++r) {
            int ys = y0 - 4 + r;
            if ((unsigned)ys < 32u) {
                f16x2 h = {(_Float16)pa[(ys << 5) + sx], (_Float16)pb[(ys << 5) + sx]};
                *(f16x2*)&tile[r * ROWSTR + (4 + sx) * CSTR + (c2 << 1)] = h;
            }
        }
    }
    __syncthreads();

    // ---- compute: flat tap loop, dx outer / dy inner, B ring of WR rows ---
    const _Float16* wg = Wh + ((size_t)(e * TAPS) * 2 + g) * 2048 + aoff;
    const _Float16* bt = tile + boff;
    int tb = wave * WR;     // first tile row of wave's output

    f16x8 F[WR][2];         // B ring: slot = (absolute row offset) & (WR-1)
    #pragma unroll
    for (int tp = 0; tp < 81; ++tp) {
        const int dx = tp / 9, dy = tp % 9;
        const _Float16* wp = wg + (dy * 9 + dx) * 4096;
        f16x8 A0 = *(const f16x8*)(wp);
        f16x8 A1 = *(const f16x8*)(wp + 512);
        f16x8 A2 = *(const f16x8*)(wp + 1024);
        f16x8 A3 = *(const f16x8*)(wp + 1536);
        const _Float16* brow = bt + dx * CSTR;
        if (dy == 0) {      // prime rows m = 0..WR-2
            #pragma unroll
            for (int m = 0; m < WR - 1; ++m) {
                F[m & (WR - 1)][0] = *(const f16x8*)(brow + (tb + m) * ROWSTR);
                F[m & (WR - 1)][1] = *(const f16x8*)(brow + (tb + m) * ROWSTR + 16 * CSTR);
            }
        }
        {   // fresh row m = dy + WR - 1 (used by this tap's last k)
            const int m = dy + WR - 1;
            F[m & (WR - 1)][0] = *(const f16x8*)(brow + (tb + m) * ROWSTR);
            F[m & (WR - 1)][1] = *(const f16x8*)(brow + (tb + m) * ROWSTR + 16 * CSTR);
        }
        #pragma unroll
        for (int k = 0; k < WR; ++k) {      // ascending: fresh-row MFMAs last
            #pragma unroll
            for (int cb = 0; cb < 2; ++cb) {
                const int sl = (dy + k) & (WR - 1);
                a[0][2 * k + cb] = __builtin_amdgcn_mfma_f32_16x16x32_f16(A0, F[sl][cb], a[0][2 * k + cb], 0, 0, 0);
                a[1][2 * k + cb] = __builtin_amdgcn_mfma_f32_16x16x32_f16(A1, F[sl][cb], a[1][2 * k + cb], 0, 0, 0);
                a[2][2 * k + cb] = __builtin_amdgcn_mfma_f32_16x16x32_f16(A2, F[sl][cb], a[2][2 * k + cb], 0, 0, 0);
                a[3][2 * k + cb] = __builtin_amdgcn_mfma_f32_16x16x32_f16(A3, F[sl][cb], a[3][2 * k + cb], 0, 0, 0);
            }
        }
    }

    // ---- epilogue: atomic fp32 add into acc (+ identity, g==0 only) -------
    // C/D layout: col = lane&15 (px), row = (lane>>4)*4 + reg (o within frag)
    float w0 = (g == 0) ? sw[e * 12] : 0.f;
    #pragma unroll
    for (int of = 0; of < 4; ++of) {
        #pragma unroll
        for (int j = 0; j < 4; ++j) {
            int o = (of << 4) + ((lane >> 4) << 2) + j;
            int ch = ide[o];
            size_t base = ((size_t)n * CF + ch) << 10;
            float* ap = acc + base;
            const float* sp = s + base;
            #pragma unroll
            for (int k = 0; k < WR; ++k) {
                int y = y0 + wave * WR + k;
                #pragma unroll
                for (int cb = 0; cb < 2; ++cb) {
                    int off = (y << 5) + (cb << 4) + (lane & 15);
                    float v = a[of][2 * k + cb][j];
                    if (g == 0) v += w0 * sp[off];
                    atomicAdd(ap + off, v);
                }
            }
        }
    }
}

extern "C" void kernel_launch(void* const* d_in, const int* in_sizes, int n_in,
                              void* d_out, int out_size, void* d_ws, size_t ws_size,
                              hipStream_t stream) {
    const float* x    = (const float*)d_in[0];
    const float* arch = (const float*)d_in[1];
    const float* norms= (const float*)d_in[2];
    const int*   idx  = (const int*)d_in[3];
    const float* w3   = (const float*)d_in[4];
    const float* w5   = (const float*)d_in[5];
    const float* w7   = (const float*)d_in[6];
    const float* w1   = (const float*)d_in[7];
    const float* s3dw = (const float*)d_in[8];
    const float* s3pw = (const float*)d_in[9];
    const float* s5dw = (const float*)d_in[10];
    const float* s5pw = (const float*)d_in[11];
    const float* d3   = (const float*)d_in[12];
    const float* d5   = (const float*)d_in[13];
    float* out = (float*)d_out;

    const size_t S = (size_t)NB * CF * HW * HW;  // 16,777,216 floats
    float* st1 = (float*)d_ws;
    float* st2 = st1 + S;
    float* st3 = st2 + S;
    _Float16* Wh = (_Float16*)(st3 + S);         // 10*81*2*64*32 halves = 6.64 MB
    float* sw = (float*)(Wh + (size_t)NEDGE * TAPS * 2 * 2048);

    softmax_kernel<<<1, 64, 0, stream>>>(arch, norms, sw);
    build_w<<<(NEDGE * TAPS * 2 * 2048) / 256, 256, 0, stream>>>(
        w3, w5, w7, w1, s3dw, s3pw, s5dw, s5pw, d3, d5, sw, Wh);

    float* states[5] = {(float*)x, st1, st2, st3, out};
    for (int node = 0; node < 4; ++node) {
        int ebase = node * (node + 1) / 2;
        pool_node<<<(int)(S / 8 / 256), 256, 0, stream>>>(
            states[0], states[1], states[2], states[3],
            states[node + 1], sw, ebase, node + 1);
        if (node == 0) {
            // 1 edge: 2-row waves -> 512 blocks (fills the GPU)
            conv_node<2><<<dim3(NB * 4, 1, 2), 256, 0, stream>>>(
                states[0], states[1], states[2], states[3],
                states[1], Wh, idx, sw, ebase);
        } else {
            conv_node<4><<<dim3(NB * 2, node + 1, 2), 256, 0, stream>>>(
                states[0], states[1], states[2], states[3],
                states[node + 1], Wh, idx, sw, ebase);
        }
    }
}